// Round 1
// baseline (350.654 us; speedup 1.0000x reference)
//
#include <hip/hip_runtime.h>
#include <math.h>

#define PI_F 3.14159265358979323846f

constexpr int NM = 544;   // 32*17 modes
// weight rows 0..16 -> kx 0..16 ; rows 17..31 -> kx 113..127

// ---------------- K1: forward truncated DFT ----------------
// grid 1024 = b*128+t, block 128 (thread = y column)
__global__ __launch_bounds__(128) void k_fwd(const float* __restrict__ X,
                                             float2* __restrict__ Xf) {
  __shared__ float2 tw[128];       // e^{-2pi i j/128}
  __shared__ float2 tmp[17][129];  // column-DFT rows 0..16 (rest by conjugate symmetry)
  const int y = threadIdx.x;
  {
    float s, c;
    sincosf(-2.0f * PI_F * (float)y / 128.0f, &s, &c);
    tw[y] = make_float2(c, s);
  }
  float2 acc[17];
#pragma unroll
  for (int r = 0; r < 17; ++r) acc[r] = make_float2(0.f, 0.f);
  __syncthreads();

  const float* xp = X + (size_t)blockIdx.x * 16384 + y;
  for (int x = 0; x < 128; ++x) {
    float v = xp[(size_t)x * 128];
    int j = 0;
#pragma unroll
    for (int r = 0; r < 17; ++r) {
      float2 w = tw[j];                    // j = (r*x) & 127, uniform -> broadcast
      acc[r].x = fmaf(v, w.x, acc[r].x);
      acc[r].y = fmaf(v, w.y, acc[r].y);
      j = (j + x) & 127;
    }
  }
#pragma unroll
  for (int r = 0; r < 17; ++r) tmp[r][y] = acc[r];
  __syncthreads();

  float2* outp = Xf + (size_t)blockIdx.x * NM;
  for (int o = y; o < NM; o += 128) {
    int r = o / 17;
    int ky = o - r * 17;
    int r2 = (r < 17) ? r : (32 - r);      // conjugate source row
    float sgn = (r < 17) ? 1.f : -1.f;
    float zx = 0.f, zy = 0.f;
    int j = 0;
    for (int yy = 0; yy < 128; ++yy) {
      float2 v = tmp[r2][yy];
      float vy = v.y * sgn;
      float2 w = tw[j];                    // e^{-2pi i yy*ky/128}
      zx += v.x * w.x - vy * w.y;
      zy += v.x * w.y + vy * w.x;
      j = (j + ky) & 127;
    }
    const float inv = 1.0f / 16384.0f;     // norm='forward' on rfft2
    outp[o] = make_float2(zx * inv, zy * inv);
  }
}

// ---------------- K2: per-mode skew-Hermitian channel mix ----------------
// grid 256: ct = blk&63 (c-tile of 2), chunk = blk>>6 (t-tile of 32)
// block 576 threads, thread = mode m (<544). All weight reads coalesced along m.
__global__ __launch_bounds__(576) void k_mix(const float* __restrict__ Wre,
                                             const float* __restrict__ Wim,
                                             const float2* __restrict__ Xf,
                                             float2* __restrict__ Yp) {
  const int m = threadIdx.x;
  if (m >= NM) return;
  const int ct = blockIdx.x & 63;
  const int chunk = blockIdx.x >> 6;
  const int c0 = ct * 2;
  float ax[2][8], ay[2][8];
#pragma unroll
  for (int cc = 0; cc < 2; ++cc)
#pragma unroll
    for (int b = 0; b < 8; ++b) { ax[cc][b] = 0.f; ay[cc][b] = 0.f; }

  const int t0 = chunk * 32;
  for (int tt = 0; tt < 32; ++tt) {
    const int t = t0 + tt;
    float wr[2], wi[2];
#pragma unroll
    for (int cc = 0; cc < 2; ++cc) {
      const int c = c0 + cc;
      size_t ia = (size_t)(c * 128 + t) * NM + m;
      size_t ib = (size_t)(t * 128 + c) * NM + m;
      wr[cc] = Wre[ia] - Wre[ib];          // Weff = W - conj(W^T)
      wi[cc] = Wim[ia] + Wim[ib];
    }
#pragma unroll
    for (int b = 0; b < 8; ++b) {
      float2 xv = Xf[(size_t)(b * 128 + t) * NM + m];
#pragma unroll
      for (int cc = 0; cc < 2; ++cc) {
        ax[cc][b] = fmaf(wr[cc], xv.x, fmaf(-wi[cc], xv.y, ax[cc][b]));
        ay[cc][b] = fmaf(wr[cc], xv.y, fmaf(wi[cc], xv.x, ay[cc][b]));
      }
    }
  }
#pragma unroll
  for (int b = 0; b < 8; ++b)
#pragma unroll
    for (int cc = 0; cc < 2; ++cc)
      Yp[(size_t)((chunk * 8 + b) * 128 + (c0 + cc)) * NM + m] =
          make_float2(ax[cc][b], ay[cc][b]);
}

// ---------------- K3: reduce partials + inverse transform ----------------
// grid 1024 = b*128+c, block 256
__global__ __launch_bounds__(256) void k_inv(const float2* __restrict__ Yp,
                                             float* __restrict__ out) {
  __shared__ float2 Ys[NM];
  __shared__ float2 Z[128 * 17];
  __shared__ float2 tw[128];        // e^{+2pi i j/128}
  __shared__ float2 ctab[17][128];  // (w*cos, w*sin), w = (ky==0 ? 1 : 2)
  const int tid = threadIdx.x;
  const int b = blockIdx.x >> 7;
  const int c = blockIdx.x & 127;

  if (tid < 128) {
    float s, cc;
    sincosf(2.0f * PI_F * (float)tid / 128.0f, &s, &cc);
    tw[tid] = make_float2(cc, s);
  }
  for (int o = tid; o < 17 * 128; o += 256) {
    int ky = o >> 7, yy = o & 127;
    float s, cc;
    sincosf(2.0f * PI_F * (float)((ky * yy) & 127) / 128.0f, &s, &cc);
    float w = (ky == 0) ? 1.f : 2.f;
    ctab[ky][yy] = make_float2(w * cc, w * s);
  }
  // Phase A: sum the 4 t-chunk partials
  for (int o = tid; o < NM; o += 256) {
    float sx = 0.f, sy = 0.f;
#pragma unroll
    for (int ch = 0; ch < 4; ++ch) {
      float2 v = Yp[(size_t)((ch * 8 + b) * 128 + c) * NM + o];
      sx += v.x; sy += v.y;
    }
    Ys[o] = make_float2(sx, sy);
  }
  __syncthreads();

  // Phase B: inverse DFT along rows: Z[x,ky] = sum_r Ys[r,ky] e^{+2pi i f(r) x/128}
  for (int o = tid; o < 128 * 17; o += 256) {
    int x = o / 17;
    int ky = o - x * 17;
    float zx = 0.f, zy = 0.f;
#pragma unroll
    for (int r = 0; r < 32; ++r) {
      int f = (r < 17) ? r : (r + 96);
      int j = (f * x) & 127;
      float2 Yv = Ys[r * 17 + ky];
      float2 w = tw[j];
      zx += Yv.x * w.x - Yv.y * w.y;
      zy += Yv.x * w.y + Yv.y * w.x;
    }
    Z[o] = make_float2(zx, zy);
  }
  __syncthreads();

  // Phase C: real reconstruction along y (C2R: imag of ky=0 bin discarded)
  float* op = out + (size_t)blockIdx.x * 16384;
  for (int o = tid; o < 16384; o += 256) {
    int x = o >> 7, yy = o & 127;
    const float2* zr = &Z[x * 17];
    float s = 0.f;
#pragma unroll
    for (int ky = 0; ky < 17; ++ky) {
      float2 zv = zr[ky];
      float2 cv = ctab[ky][yy];
      s += zv.x * cv.x - zv.y * cv.y;
    }
    op[o] = s;
  }
}

extern "C" void kernel_launch(void* const* d_in, const int* in_sizes, int n_in,
                              void* d_out, int out_size, void* d_ws, size_t ws_size,
                              hipStream_t stream) {
  const float* X   = (const float*)d_in[0];
  const float* Wre = (const float*)d_in[1];
  const float* Wim = (const float*)d_in[2];
  float* out = (float*)d_out;

  float2* Xf = (float2*)d_ws;                    // 1024*544 float2 = 4.45 MB
  float2* Yp = Xf + (size_t)1024 * NM;           // 4*1024*544 float2 = 17.8 MB

  k_fwd<<<dim3(1024), dim3(128), 0, stream>>>(X, Xf);
  k_mix<<<dim3(256), dim3(576), 0, stream>>>(Wre, Wim, Xf, Yp);
  k_inv<<<dim3(1024), dim3(256), 0, stream>>>(Yp, out);
}

// Round 2
// 345.025 us; speedup vs baseline: 1.0163x; 1.0163x over previous
//
#include <hip/hip_runtime.h>
#include <math.h>

#define PI_F 3.14159265358979323846f

constexpr int NM = 544;   // 32 kx-rows * 17 ky-cols of retained modes

// ---- workspace byte offsets (all 16B-aligned) ----
constexpr size_t OFF_F1 = 0;        // 128*34 floats  (col-DFT twiddle, /16384 folded)   17408 B
constexpr size_t OFF_F2 = 17408;    // 128*36 floats  (row-DFT twiddle, ky<18 padded)    18432 B
constexpr size_t OFF_G  = 35840;    // 32*128 float2  (inverse x-twiddle)                32768 B
constexpr size_t OFF_CT = 68608;    // 17*128 float2  (C2R cos/sin, weight folded)       17408 B
constexpr size_t OFF_XF = 86016;    // 1024*544 float2                                   4456448 B
constexpr size_t OFF_YS = 4542464;  // 1024*544 float2 (reduced, [ky*32+r] order)        4456448 B
constexpr size_t OFF_YP = 8998912;  // 4*1024*544 float2 partials; reused as Z (1024*17*128 f2)

// ---------------- K0: twiddle tables ----------------
__global__ __launch_bounds__(256) void k_tab(float* __restrict__ F1, float* __restrict__ F2,
                                             float2* __restrict__ G, float2* __restrict__ CT) {
  const int t0 = blockIdx.x * 256 + threadIdx.x;
  const int N = gridDim.x * 256;
  const float inv = 1.0f / 16384.0f;
  for (int i = t0; i < 128 * 17; i += N) {
    int x = i / 17, r = i - 17 * x;
    float s, c; sincosf(-2.f * PI_F * (float)((x * r) & 127) / 128.f, &s, &c);
    F1[x * 34 + 2 * r] = c * inv; F1[x * 34 + 2 * r + 1] = s * inv;
  }
  for (int i = t0; i < 128 * 18; i += N) {
    int y = i / 18, k = i - 18 * y;
    if (k == 17) { F2[y * 36 + 34] = 0.f; F2[y * 36 + 35] = 0.f; }
    else {
      float s, c; sincosf(-2.f * PI_F * (float)((y * k) & 127) / 128.f, &s, &c);
      F2[y * 36 + 2 * k] = c; F2[y * 36 + 2 * k + 1] = s;
    }
  }
  for (int i = t0; i < 32 * 128; i += N) {
    int r = i >> 7, x = i & 127;
    int f = (r < 17) ? r : r + 96;
    float s, c; sincosf(2.f * PI_F * (float)((f * x) & 127) / 128.f, &s, &c);
    G[i] = make_float2(c, s);
  }
  for (int i = t0; i < 17 * 128; i += N) {
    int k = i >> 7;
    float w = k ? 2.f : 1.f;
    float s, c; sincosf(2.f * PI_F * (float)((k * (i & 127)) & 127) / 128.f, &s, &c);
    CT[i] = make_float2(w * c, w * s);
  }
}

// ---------------- K1: fused forward truncated DFT ----------------
// grid 1024 = b*128+t, block 128 (2 waves)
__global__ __launch_bounds__(128) void k_fwd(const float* __restrict__ X,
                                             const float* __restrict__ F1,
                                             const float* __restrict__ F2,
                                             float2* __restrict__ Xf) {
  __shared__ float2 tmp[128][17];   // column-DFT result [y][r]
  const int tid = threadIdx.x;
  const int bt = blockIdx.x;

  // Phase 1: col[r][y] = sum_x X[x][y] * e^{-2pi i r x/128} / 16384. Lane = y.
  // F1 address depends only on loop var x -> scalar s_load twiddles.
  float2 acc[17];
#pragma unroll
  for (int r = 0; r < 17; ++r) acc[r] = make_float2(0.f, 0.f);
  const float* xp = X + (size_t)bt * 16384 + tid;
#pragma unroll 4
  for (int x = 0; x < 128; ++x) {
    float v = xp[(size_t)x * 128];
    const float* f = F1 + x * 34;
#pragma unroll
    for (int r = 0; r < 17; ++r) {
      acc[r].x = fmaf(v, f[2 * r], acc[r].x);
      acc[r].y = fmaf(v, f[2 * r + 1], acc[r].y);
    }
  }
#pragma unroll
  for (int r = 0; r < 17; ++r) tmp[tid][r] = acc[r];
  __syncthreads();

  // Phase 2: Xf[r][ky] = sum_y col[f(r)][y] e^{-2pi i ky y/128}.
  // wave w owns ky group (0..8 / 9..16); lanes = (r:32, yh:2); y split by yh, shfl-reduced.
  const int lane = tid & 63;
  const int w = tid >> 6;
  const int r = lane & 31;
  const int yh = lane >> 5;
  const int r2 = (r < 17) ? r : 32 - r;      // conjugate source row
  const float sgn = (r < 17) ? 1.f : -1.f;
  float2 a2[9];
#pragma unroll
  for (int i = 0; i < 9; ++i) a2[i] = make_float2(0.f, 0.f);
  const float* f2b = F2 + w * 18 + yh * 36;
  for (int yl = 0; yl < 64; ++yl) {
    float2 tv = tmp[2 * yl + yh][r2];
    float tvy = tv.y * sgn;
    const float* f = f2b + yl * 72;
#pragma unroll
    for (int i = 0; i < 9; ++i) {
      float cr = f[2 * i], ci = f[2 * i + 1];
      a2[i].x = fmaf(tv.x, cr, fmaf(-tvy, ci, a2[i].x));
      a2[i].y = fmaf(tv.x, ci, fmaf(tvy, cr, a2[i].y));
    }
  }
#pragma unroll
  for (int i = 0; i < 9; ++i) {
    a2[i].x += __shfl_xor(a2[i].x, 32);
    a2[i].y += __shfl_xor(a2[i].y, 32);
  }
  const int nky = w ? 8 : 9;
  if (lane < 32) {
    for (int i = 0; i < nky; ++i) {
      int ky = w * 9 + i;
      Xf[(size_t)bt * NM + r * 17 + ky] = a2[i];   // weight-native m = r*17+ky
    }
  }
}

// ---------------- K2: skew-Hermitian channel mix ----------------
// grid 512 = c(128) x chunk(4); block 576 = modes m (coalesced weight reads)
__global__ __launch_bounds__(576) void k_mix(const float* __restrict__ Wre,
                                             const float* __restrict__ Wim,
                                             const float2* __restrict__ Xf,
                                             float2* __restrict__ Yp) {
  const int m = threadIdx.x;
  if (m >= NM) return;
  const int c = blockIdx.x & 127;
  const int chunk = blockIdx.x >> 7;
  float2 acc[8];
#pragma unroll
  for (int b = 0; b < 8; ++b) acc[b] = make_float2(0.f, 0.f);
  const int t0 = chunk * 32;
#pragma unroll 2
  for (int tt = 0; tt < 32; ++tt) {
    const int t = t0 + tt;
    float wr = Wre[(size_t)(c * 128 + t) * NM + m] - Wre[(size_t)(t * 128 + c) * NM + m];
    float wi = Wim[(size_t)(c * 128 + t) * NM + m] + Wim[(size_t)(t * 128 + c) * NM + m];
#pragma unroll
    for (int b = 0; b < 8; ++b) {
      float2 xv = Xf[(size_t)(b * 128 + t) * NM + m];
      acc[b].x = fmaf(wr, xv.x, fmaf(-wi, xv.y, acc[b].x));
      acc[b].y = fmaf(wr, xv.y, fmaf(wi, xv.x, acc[b].y));
    }
  }
#pragma unroll
  for (int b = 0; b < 8; ++b)
    Yp[(size_t)chunk * 1024 * NM + (size_t)(b * 128 + c) * NM + m] = acc[b];
}

// ---------------- K3: reduce 4 partials + permute m -> [ky*32+r] ----------------
__global__ __launch_bounds__(256) void k_red(const float2* __restrict__ Yp,
                                             float2* __restrict__ Ys) {
  int i = blockIdx.x * 256 + threadIdx.x;     // i < 1024*544
  if (i >= 1024 * NM) return;
  int bc = i / NM, m = i - bc * NM;
  int r = m / 17, ky = m - r * 17;
  float2 s = make_float2(0.f, 0.f);
#pragma unroll
  for (int ch = 0; ch < 4; ++ch) {
    float2 v = Yp[(size_t)ch * 1024 * NM + i];
    s.x += v.x; s.y += v.y;
  }
  Ys[(size_t)bc * NM + ky * 32 + r] = s;
}

// ---------------- K4: inverse row DFT (scalar Ys, per-lane G) ----------------
// grid 512, block 256 = 2 slices x 2 x-halves (wave each)
__global__ __launch_bounds__(256) void k_invB(const float* __restrict__ Ys,
                                              const float2* __restrict__ G,
                                              float2* __restrict__ Z) {
  const int tid = threadIdx.x;
  const int lane = tid & 63;
  const int bc = __builtin_amdgcn_readfirstlane(blockIdx.x * 2 + (tid >> 7));
  const int xh = __builtin_amdgcn_readfirstlane((tid >> 6) & 1);
  const int x = xh * 64 + lane;
  float2 g[32];
#pragma unroll
  for (int r = 0; r < 32; ++r) g[r] = G[r * 128 + x];
  const float* yb = Ys + (size_t)bc * (NM * 2);
  float2* zb = Z + (size_t)bc * (17 * 128) + x;
  for (int ky = 0; ky < 17; ++ky) {
    const float* yk = yb + ky * 64;      // 32 consecutive complex -> s_load
    float zr = 0.f, zi = 0.f;
#pragma unroll
    for (int r = 0; r < 32; ++r) {
      float ar = yk[2 * r], ai = yk[2 * r + 1];
      zr = fmaf(ar, g[r].x, fmaf(-ai, g[r].y, zr));
      zi = fmaf(ar, g[r].y, fmaf(ai, g[r].x, zi));
    }
    zb[ky * 128] = make_float2(zr, zi);  // Z[bc][ky][x], coalesced
  }
}

// ---------------- K5: C2R reconstruction (scalar Z, per-lane cos/sin) ----------------
// grid 1024 = (b,c), block 256: lanes = yy, waves split x halves
__global__ __launch_bounds__(256) void k_invC(const float* __restrict__ Z,
                                              const float2* __restrict__ CT,
                                              float* __restrict__ out) {
  const int tid = threadIdx.x;
  const int yy = tid & 127;
  const int xh = __builtin_amdgcn_readfirstlane(tid >> 7);
  const int bc = blockIdx.x;
  float2 ct[17];
#pragma unroll
  for (int k = 0; k < 17; ++k) ct[k] = CT[k * 128 + yy];
  const float* zb = Z + (size_t)bc * (17 * 128 * 2);
  float* op = out + (size_t)bc * 16384;
#pragma unroll 2
  for (int xi = 0; xi < 64; ++xi) {
    int x = xh * 64 + xi;
    const float* zp = zb + 2 * x;        // uniform address -> s_load per ky
    float s = 0.f;
#pragma unroll
    for (int k = 0; k < 17; ++k) {
      float zr = zp[k * 256], zi = zp[k * 256 + 1];
      s = fmaf(zr, ct[k].x, fmaf(-zi, ct[k].y, s));
    }
    op[x * 128 + yy] = s;                // coalesced 64 MB store
  }
}

extern "C" void kernel_launch(void* const* d_in, const int* in_sizes, int n_in,
                              void* d_out, int out_size, void* d_ws, size_t ws_size,
                              hipStream_t stream) {
  const float* X   = (const float*)d_in[0];
  const float* Wre = (const float*)d_in[1];
  const float* Wim = (const float*)d_in[2];
  float* out = (float*)d_out;

  char* ws = (char*)d_ws;
  float*  F1 = (float*)(ws + OFF_F1);
  float*  F2 = (float*)(ws + OFF_F2);
  float2* G  = (float2*)(ws + OFF_G);
  float2* CT = (float2*)(ws + OFF_CT);
  float2* Xf = (float2*)(ws + OFF_XF);
  float2* Ys = (float2*)(ws + OFF_YS);
  float2* Yp = (float2*)(ws + OFF_YP);
  float2* Z  = Yp;                        // Yp dead after k_red; reuse as Z

  k_tab <<<32, 256, 0, stream>>>(F1, F2, G, CT);
  k_fwd <<<1024, 128, 0, stream>>>(X, F1, F2, Xf);
  k_mix <<<512, 576, 0, stream>>>(Wre, Wim, Xf, Yp);
  k_red <<<2176, 256, 0, stream>>>(Yp, Ys);
  k_invB<<<512, 256, 0, stream>>>((const float*)Ys, G, Z);
  k_invC<<<1024, 256, 0, stream>>>((const float*)Z, CT, out);
}